// Round 2
// baseline (1045.453 us; speedup 1.0000x reference)
//
#include <hip/hip_runtime.h>
#include <hip/hip_bf16.h>

// Problem constants
#define BATCH 8
#define SEQLEN 8192
#define H_IN 128
#define H_OUT 128
#define NS 256
#define M_TOT (BATCH * SEQLEN)          // 65536
#define CL 64                            // scan chunk length
#define NCH (SEQLEN / CL)                // 128 chunks per batch
#define Y_FLOATS ((size_t)BATCH * SEQLEN * H_OUT)   // 8388608

// Output-layout modes (detected from out_size at runtime):
//  mode A (out_size = 25,167,872): d_out = [y f32 | Re(states) f32]; Im in ws.
//  mode B (out_size = 41,947,136): d_out = [y f32 | states complex64 as float pairs].
// All kernels take (reP, imP, es, rs): state element (b,l,n):
//   re at reP[(b*(SEQLEN+1)+l)*rs + n*es], im at imP[same offset].
// mode A: es=1 rs=256 imP=ws buffer; mode B: es=2 rs=512 imP=reP+1.

// ---------------------------------------------------------------------------
// Setup: lambdas, lambda^CL, Bfi = interleaved gamma*Bp (512x128),
// W = [C_re | -C_im | D] (128 x 640)
// ---------------------------------------------------------------------------
__global__ __launch_bounds__(256) void setup_kernel(
    const float* __restrict__ nu_log, const float* __restrict__ theta_log,
    const float* __restrict__ gamma_log,
    const float* __restrict__ Bp_re, const float* __restrict__ Bp_im,
    const float* __restrict__ C_re, const float* __restrict__ C_im,
    const float* __restrict__ D,
    float* __restrict__ Bfi, float* __restrict__ W,
    float* __restrict__ lamRe, float* __restrict__ lamIm,
    float* __restrict__ lamPRe, float* __restrict__ lamPIm) {
  const int t = threadIdx.x;  // 0..255
  {
    float e  = expf(nu_log[t]);
    float th = expf(theta_log[t]);
    float r  = expf(-e);
    lamRe[t] = r * cosf(th);
    lamIm[t] = r * sinf(th);
    float rP  = expf(-(float)CL * e);
    float thP = (float)CL * th;
    lamPRe[t] = rP * cosf(thP);
    lamPIm[t] = rP * sinf(thP);
    float g = expf(gamma_log[t]);
    const float* br = Bp_re + (size_t)t * H_IN;
    const float* bi = Bp_im + (size_t)t * H_IN;
    float* o0 = Bfi + (size_t)(2 * t) * H_IN;
    float* o1 = Bfi + (size_t)(2 * t + 1) * H_IN;
    for (int h = 0; h < H_IN; h++) { o0[h] = g * br[h]; o1[h] = g * bi[h]; }
  }
  // W: 128 x 640 = [C_re (256) | -C_im (256) | D (128)]
  for (int i = t; i < H_OUT * 640; i += 256) {
    int o = i / 640, k = i % 640;
    float v;
    if (k < NS)            v = C_re[(size_t)o * NS + k];
    else if (k < 2 * NS)   v = -C_im[(size_t)o * NS + (k - NS)];
    else                   v = D[(size_t)o * H_IN + (k - 2 * NS)];
    W[i] = v;
  }
}

// ---------------------------------------------------------------------------
// GEMM1: Bu[m][c] = sum_h u[m][h] * Bfi[c][h], c in 0..511 (even=re, odd=im of
// state n=c/2). Written to (reP,imP) at row (b*(SEQLEN+1) + l + 1).
// Tiles: BM=64, BN=64(float cols), BK=64; 256 threads, 4x4 per thread.
// ---------------------------------------------------------------------------
__global__ __launch_bounds__(256) void gemm_bu(
    const float* __restrict__ u, const float* __restrict__ Bfi,
    float* __restrict__ reP, float* __restrict__ imP, int es, int rs) {
  __shared__ float At[64][68];
  __shared__ float Bt[64][68];
  const int t = threadIdx.x;
  const int m0 = blockIdx.x * 64;
  const int n0 = blockIdx.y * 64;      // float-column base (0..448, step 64)
  const int tr = t >> 4, tc = t & 15;
  const int sr = t >> 2, scb = (t & 3) * 4;
  float acc[4][4] = {};
  const float* aSrc = u + (size_t)(m0 + sr) * H_IN;
  const float* bSrc = Bfi + (size_t)(n0 + sr) * H_IN;
  for (int kt = 0; kt < 2; kt++) {
#pragma unroll
    for (int j = 0; j < 4; j++) {
      int c = scb + j * 16;
      float4 v = *(const float4*)(aSrc + kt * 64 + c);
      At[c][sr] = v.x; At[c + 1][sr] = v.y; At[c + 2][sr] = v.z; At[c + 3][sr] = v.w;
      float4 w = *(const float4*)(bSrc + kt * 64 + c);
      Bt[c][sr] = w.x; Bt[c + 1][sr] = w.y; Bt[c + 2][sr] = w.z; Bt[c + 3][sr] = w.w;
    }
    __syncthreads();
#pragma unroll
    for (int k = 0; k < 64; k++) {
      const float4 a = *(const float4*)&At[k][tr << 2];
      const float4 b = *(const float4*)&Bt[k][tc << 2];
      float ar[4] = {a.x, a.y, a.z, a.w};
      float br[4] = {b.x, b.y, b.z, b.w};
#pragma unroll
      for (int i = 0; i < 4; i++)
#pragma unroll
        for (int j = 0; j < 4; j++) acc[i][j] = fmaf(ar[i], br[j], acc[i][j]);
    }
    __syncthreads();
  }
  const int b = m0 >> 13;
  const int l1 = (m0 & (SEQLEN - 1)) + (tr << 2) + 1;
#pragma unroll
  for (int i = 0; i < 4; i++) {
    size_t row = (size_t)b * (SEQLEN + 1) + l1 + i;
    if (es == 1) {
      // split mode: cols n0+tc*4 .. +3 = re,im,re,im of n = (n0>>1)+tc*2, +1
      size_t off = row * (size_t)rs + (size_t)(n0 >> 1) + (tc << 1);
      *(float2*)(reP + off) = make_float2(acc[i][0], acc[i][2]);
      *(float2*)(imP + off) = make_float2(acc[i][1], acc[i][3]);
    } else {
      // interleaved mode: contiguous float4
      size_t off = row * (size_t)rs + n0 + (tc << 2);
      *(float4*)(reP + off) =
          make_float4(acc[i][0], acc[i][1], acc[i][2], acc[i][3]);
    }
  }
}

// ---------------------------------------------------------------------------
// ScanA: per-chunk carry (local scan from zero). Block = (b, chunk), thread = n.
// ---------------------------------------------------------------------------
__global__ __launch_bounds__(256) void scanA(
    const float* __restrict__ reP, const float* __restrict__ imP, int es, int rs,
    const float* __restrict__ lamRe, const float* __restrict__ lamIm,
    float* __restrict__ carries) {
  const int blk = blockIdx.x;            // b*NCH + c
  const int b = blk >> 7, c = blk & (NCH - 1);
  const int n = threadIdx.x;
  const float lr = lamRe[n], li = lamIm[n];
  float xr = 0.f, xi = 0.f;
  size_t off = ((size_t)b * (SEQLEN + 1) + (size_t)c * CL + 1) * rs + (size_t)n * es;
  const float* pr = reP + off;
  const float* pi = imP + off;
#pragma unroll 4
  for (int t = 0; t < CL; t++) {
    float br = *pr, bi = *pi;
    float nr = fmaf(lr, xr, fmaf(-li, xi, br));
    float ni = fmaf(lr, xi, fmaf(li, xr, bi));
    xr = nr; xi = ni;
    pr += rs; pi += rs;
  }
  size_t ci = ((size_t)blk * NS + n) * 2;
  carries[ci] = xr; carries[ci + 1] = xi;
}

// ---------------------------------------------------------------------------
// ScanB: scan carries across chunks per (b,n) chain (2048 chains).
// starts[b][c][n] = state at the beginning of chunk c.
// ---------------------------------------------------------------------------
__global__ __launch_bounds__(256) void scanB(
    const float* __restrict__ carries, const float* __restrict__ lamPRe,
    const float* __restrict__ lamPIm, float* __restrict__ starts) {
  const int id = blockIdx.x * 256 + threadIdx.x;  // 0..2047
  const int b = id >> 8, n = id & (NS - 1);
  const float lr = lamPRe[n], li = lamPIm[n];
  float xr = 0.f, xi = 0.f;
  for (int c = 0; c < NCH; c++) {
    size_t idx = (((size_t)b * NCH + c) * NS + n) * 2;
    starts[idx] = xr; starts[idx + 1] = xi;
    float cr = carries[idx], ci = carries[idx + 1];
    float nr = fmaf(lr, xr, fmaf(-li, xi, cr));
    float ni = fmaf(lr, xi, fmaf(li, xr, ci));
    xr = nr; xi = ni;
  }
}

// ---------------------------------------------------------------------------
// ScanC: in-place fixup — read Bu, apply recurrence from chunk-start state,
// write final states back. Chunk 0 also zeros the x0 row.
// ---------------------------------------------------------------------------
__global__ __launch_bounds__(256) void scanC(
    float* __restrict__ reP, float* __restrict__ imP, int es, int rs,
    const float* __restrict__ lamRe, const float* __restrict__ lamIm,
    const float* __restrict__ starts) {
  const int blk = blockIdx.x;
  const int b = blk >> 7, c = blk & (NCH - 1);
  const int n = threadIdx.x;
  const float lr = lamRe[n], li = lamIm[n];
  size_t sidx = (((size_t)b * NCH + c) * NS + n) * 2;
  float xr = starts[sidx], xi = starts[sidx + 1];
  if (c == 0) {
    size_t o0 = ((size_t)b * (SEQLEN + 1)) * rs + (size_t)n * es;
    reP[o0] = 0.f; imP[o0] = 0.f;
  }
  size_t off = ((size_t)b * (SEQLEN + 1) + (size_t)c * CL + 1) * rs + (size_t)n * es;
  float* pr = reP + off;
  float* pi = imP + off;
#pragma unroll 4
  for (int t = 0; t < CL; t++) {
    float br = *pr, bi = *pi;
    float nr = fmaf(lr, xr, fmaf(-li, xi, br));
    float ni = fmaf(lr, xi, fmaf(li, xr, bi));
    xr = nr; xi = ni;
    *pr = xr; *pi = xi;
    pr += rs; pi += rs;
  }
}

// ---------------------------------------------------------------------------
// GEMM2: y[m][o] = sum_{n<256} (preRe[n]*C_re[o][n] - preIm[n]*C_im[o][n])
//               + sum_h u[m][h]*D[o][h]
// K = 640: kt 0..3 from re-states, 4..7 from im-states, 8..9 from u.
// pre row for output m = (b,l) is state row l (the state BEFORE step l).
// ---------------------------------------------------------------------------
__global__ __launch_bounds__(256) void gemm_y(
    const float* __restrict__ reP, const float* __restrict__ imP, int es, int rs,
    const float* __restrict__ u, const float* __restrict__ W,
    float* __restrict__ y) {
  __shared__ float At[64][68];
  __shared__ float Bt[64][68];
  const int t = threadIdx.x;
  const int m0 = blockIdx.x * 64;
  const int n0 = blockIdx.y * 64;
  const int tr = t >> 4, tc = t & 15;
  const int lr = t >> 6, lc = t & 63;    // loader: row group 0..3, col 0..63
  const int b = m0 >> 13, l0 = m0 & (SEQLEN - 1);
  float acc[4][4] = {};
  for (int kt = 0; kt < 10; kt++) {
#pragma unroll
    for (int rr0 = 0; rr0 < 64; rr0 += 4) {
      int rr = rr0 + lr;
      float av;
      if (kt < 8) {
        size_t row = (size_t)b * (SEQLEN + 1) + l0 + rr;
        int f = kt * 64 + lc;            // 0..511
        av = (kt < 4) ? reP[row * (size_t)rs + (size_t)f * es]
                      : imP[row * (size_t)rs + (size_t)(f - 256) * es];
      } else {
        av = u[((size_t)b * SEQLEN + l0 + rr) * H_IN + (kt - 8) * 64 + lc];
      }
      At[lc][rr] = av;
      Bt[lc][rr] = W[(size_t)(n0 + rr) * 640 + kt * 64 + lc];
    }
    __syncthreads();
#pragma unroll
    for (int k = 0; k < 64; k++) {
      const float4 a = *(const float4*)&At[k][tr << 2];
      const float4 bv = *(const float4*)&Bt[k][tc << 2];
      float ar[4] = {a.x, a.y, a.z, a.w};
      float br[4] = {bv.x, bv.y, bv.z, bv.w};
#pragma unroll
      for (int i = 0; i < 4; i++)
#pragma unroll
        for (int j = 0; j < 4; j++) acc[i][j] = fmaf(ar[i], br[j], acc[i][j]);
    }
    __syncthreads();
  }
  float* out = y + (size_t)(m0 + (tr << 2)) * H_OUT + n0 + (tc << 2);
#pragma unroll
  for (int i = 0; i < 4; i++) {
    *(float4*)(out + (size_t)i * H_OUT) =
        make_float4(acc[i][0], acc[i][1], acc[i][2], acc[i][3]);
  }
}

// ---------------------------------------------------------------------------
extern "C" void kernel_launch(void* const* d_in, const int* in_sizes, int n_in,
                              void* d_out, int out_size, void* d_ws, size_t ws_size,
                              hipStream_t stream) {
  const float* u         = (const float*)d_in[0];
  const float* nu_log    = (const float*)d_in[1];
  const float* theta_log = (const float*)d_in[2];
  const float* gamma_log = (const float*)d_in[3];
  const float* Bp_re     = (const float*)d_in[4];
  const float* Bp_im     = (const float*)d_in[5];
  const float* C_re      = (const float*)d_in[6];
  const float* C_im      = (const float*)d_in[7];
  const float* D         = (const float*)d_in[8];

  float* y  = (float*)d_out;
  float* ws = (float*)d_ws;

  // small setup tables in ws
  float* Bfi    = ws;                  // 512*128 = 65536
  float* W      = Bfi + 512 * 128;     // 128*640 = 81920
  float* lamRe  = W + 128 * 640;       // 256
  float* lamIm  = lamRe + NS;
  float* lamPRe = lamIm + NS;
  float* lamPIm = lamPRe + NS;
  float* wsFree = lamPIm + NS;         // ws + 148480 floats
  const size_t smallWsFloats = 148480;

  // carries/starts live in the y region of d_out (y written last; no hazard).
  float* carries = y;                                   // 524288 floats
  float* starts  = y + (size_t)BATCH * NCH * NS * 2;    // 524288 floats

  // mode detection from out_size
  const size_t stateFloats = (size_t)BATCH * (SEQLEN + 1) * NS;  // 16,779,264
  float *reP, *imP;
  int es, rs;
  size_t needWsBytes;
  if (out_size >= (int)(Y_FLOATS + 2 * stateFloats)) {
    // mode B: interleaved complex in d_out
    reP = y + Y_FLOATS; imP = reP + 1; es = 2; rs = 512;
    needWsBytes = smallWsFloats * 4;
  } else if (out_size >= (int)(Y_FLOATS + stateFloats)) {
    // mode A: Re(states) in d_out, Im in ws
    reP = y + Y_FLOATS; imP = wsFree; es = 1; rs = 256;
    needWsBytes = (smallWsFloats + stateFloats) * 4;
  } else {
    return;  // unexpected layout: fail cleanly (no OOB writes)
  }
  if (ws_size < needWsBytes) return;  // fail cleanly -> diagnostic signal

  setup_kernel<<<1, 256, 0, stream>>>(nu_log, theta_log, gamma_log, Bp_re, Bp_im,
                                      C_re, C_im, D, Bfi, W, lamRe, lamIm,
                                      lamPRe, lamPIm);
  gemm_bu<<<dim3(M_TOT / 64, 512 / 64), 256, 0, stream>>>(u, Bfi, reP, imP, es, rs);
  scanA<<<BATCH * NCH, 256, 0, stream>>>(reP, imP, es, rs, lamRe, lamIm, carries);
  scanB<<<BATCH, 256, 0, stream>>>(carries, lamPRe, lamPIm, starts);
  scanC<<<BATCH * NCH, 256, 0, stream>>>(reP, imP, es, rs, lamRe, lamIm, starts);
  gemm_y<<<dim3(M_TOT / 64, H_OUT / 64), 256, 0, stream>>>(reP, imP, es, rs, u, W, y);
}

// Round 3
// 459.190 us; speedup vs baseline: 2.2767x; 2.2767x over previous
//
#include <hip/hip_runtime.h>
#include <hip/hip_bf16.h>

// Problem constants
#define BATCH 8
#define SEQLEN 8192
#define H_IN 128
#define H_OUT 128
#define NS 256
#define M_TOT (BATCH * SEQLEN)          // 65536
#define CL 64
#define NCH (SEQLEN / CL)                // 128
#define Y_FLOATS ((size_t)BATCH * SEQLEN * H_OUT)   // 8388608
#define SROWB (SEQLEN + 1)               // 8193 state rows per batch

// Mode A (confirmed): d_out = [y f32 | Re(states) f32], Im(states) in ws.
//   es=1, rs=256. Mode B fallback: interleaved complex in d_out, es=2, rs=512.

// ---------------------------------------------------------------------------
// setup_small: lambdas, lambda^CL, Bfi = interleaved gamma*Bp (512 x 128)
// ---------------------------------------------------------------------------
__global__ __launch_bounds__(256) void setup_small(
    const float* __restrict__ nu_log, const float* __restrict__ theta_log,
    const float* __restrict__ gamma_log,
    const float* __restrict__ Bp_re, const float* __restrict__ Bp_im,
    float* __restrict__ Bfi,
    float* __restrict__ lamRe, float* __restrict__ lamIm,
    float* __restrict__ lamPRe, float* __restrict__ lamPIm) {
  const int t = threadIdx.x;  // 0..255
  float e  = expf(nu_log[t]);
  float th = expf(theta_log[t]);
  float r  = expf(-e);
  lamRe[t] = r * cosf(th);
  lamIm[t] = r * sinf(th);
  float rP  = expf(-(float)CL * e);
  float thP = (float)CL * th;
  lamPRe[t] = rP * cosf(thP);
  lamPIm[t] = rP * sinf(thP);
  float g = expf(gamma_log[t]);
  const float4* br = (const float4*)(Bp_re + (size_t)t * H_IN);
  const float4* bi = (const float4*)(Bp_im + (size_t)t * H_IN);
  float4* o0 = (float4*)(Bfi + (size_t)(2 * t) * H_IN);
  float4* o1 = (float4*)(Bfi + (size_t)(2 * t + 1) * H_IN);
#pragma unroll 4
  for (int h = 0; h < H_IN / 4; h++) {
    float4 a = br[h], b = bi[h];
    o0[h] = make_float4(g * a.x, g * a.y, g * a.z, g * a.w);
    o1[h] = make_float4(g * b.x, g * b.y, g * b.z, g * b.w);
  }
}

// setup_W: W (128 x 640) = [C_re (256) | -C_im (256) | D (128)], one elem/thread
__global__ __launch_bounds__(256) void setup_W(
    const float* __restrict__ C_re, const float* __restrict__ C_im,
    const float* __restrict__ D, float* __restrict__ W) {
  int i = blockIdx.x * 256 + threadIdx.x;
  if (i >= H_OUT * 640) return;
  int o = i / 640, k = i - o * 640;
  float v;
  if (k < NS)          v = C_re[(size_t)o * NS + k];
  else if (k < 2 * NS) v = -C_im[(size_t)o * NS + (k - NS)];
  else                 v = D[(size_t)o * H_IN + (k - 2 * NS)];
  W[i] = v;
}

// ---------------------------------------------------------------------------
// GEMM1: Bu[m][c] = sum_h u[m][h]*Bfi[c][h], c in 0..511 (even=re, odd=im).
// BM=128, BN=128, BK=32, 256 thr, 8x8/thread, reg-prefetch next tile.
// Writes to state rows (b*8193 + l + 1).
// ---------------------------------------------------------------------------
template <int ES, int RS>
__global__ __launch_bounds__(256) void gemm_bu_k(
    const float* __restrict__ u, const float* __restrict__ Bfi,
    float* __restrict__ reP, float* __restrict__ imP) {
  __shared__ float At[32][132];
  __shared__ float Bt[32][132];
  const int t = threadIdx.x;
  const int m0 = blockIdx.x * 128;
  const int n0 = blockIdx.y * 128;     // float-col base
  const int tm = t & 15, tn = t >> 4;
  const int lr = t >> 3;               // 0..31
  const int kq = t & 7;                // 0..7
  float acc[8][8] = {};
  float4 va[4], vb[4];

  auto loadT = [&](int kt, int p, float4& a, float4& b) {
    int row = p * 32 + lr;
    int f = kt * 32 + kq * 4;
    a = *(const float4*)(u + (size_t)(m0 + row) * H_IN + f);
    b = *(const float4*)(Bfi + (size_t)(n0 + row) * H_IN + f);
  };
#pragma unroll
  for (int p = 0; p < 4; p++) loadT(0, p, va[p], vb[p]);

  const int NT = H_IN / 32;  // 4
  for (int kt = 0; kt < NT; kt++) {
#pragma unroll
    for (int p = 0; p < 4; p++) {
      int row = p * 32 + lr;
      At[kq * 4 + 0][row] = va[p].x; At[kq * 4 + 1][row] = va[p].y;
      At[kq * 4 + 2][row] = va[p].z; At[kq * 4 + 3][row] = va[p].w;
      Bt[kq * 4 + 0][row] = vb[p].x; Bt[kq * 4 + 1][row] = vb[p].y;
      Bt[kq * 4 + 2][row] = vb[p].z; Bt[kq * 4 + 3][row] = vb[p].w;
    }
    __syncthreads();
    if (kt + 1 < NT) {
#pragma unroll
      for (int p = 0; p < 4; p++) loadT(kt + 1, p, va[p], vb[p]);
    }
#pragma unroll 4
    for (int k = 0; k < 32; k++) {
      float4 a0 = *(const float4*)&At[k][tm * 4];
      float4 a1 = *(const float4*)&At[k][tm * 4 + 64];
      float4 b0 = *(const float4*)&Bt[k][tn * 4];
      float4 b1 = *(const float4*)&Bt[k][tn * 4 + 64];
      float ar[8] = {a0.x, a0.y, a0.z, a0.w, a1.x, a1.y, a1.z, a1.w};
      float br[8] = {b0.x, b0.y, b0.z, b0.w, b1.x, b1.y, b1.z, b1.w};
#pragma unroll
      for (int i = 0; i < 8; i++)
#pragma unroll
        for (int j = 0; j < 8; j++) acc[i][j] = fmaf(ar[i], br[j], acc[i][j]);
    }
    __syncthreads();
  }
  const int b = m0 >> 13;
  const int l1 = (m0 & (SEQLEN - 1)) + 1;
#pragma unroll
  for (int i = 0; i < 8; i++) {
    int mrow = tm * 4 + (i & 3) + (i >> 2) * 64;
    size_t row = (size_t)b * SROWB + l1 + mrow;
#pragma unroll
    for (int jh = 0; jh < 2; jh++) {
      int c = n0 + tn * 4 + jh * 64;  // float col, multiple of 4
      float x0 = acc[i][jh * 4 + 0], x1 = acc[i][jh * 4 + 1];
      float x2 = acc[i][jh * 4 + 2], x3 = acc[i][jh * 4 + 3];
      if (ES == 1) {
        size_t off = row * (size_t)RS + (size_t)(c >> 1);
        *(float2*)(reP + off) = make_float2(x0, x2);
        *(float2*)(imP + off) = make_float2(x1, x3);
      } else {
        size_t off = row * (size_t)RS + c;
        *(float4*)(reP + off) = make_float4(x0, x1, x2, x3);
      }
    }
  }
}

// ---------------------------------------------------------------------------
// GEMM2: y = [Re(states) | Im(states) | u] (K=640) x W^T (128).
// BM=128, BN=128 (all H_OUT), BK=32, 8x8/thread, reg-prefetch.
// A rows are PRE-states: state row l (not l+1).
// ---------------------------------------------------------------------------
template <int ES, int RS>
__global__ __launch_bounds__(256) void gemm_y_k(
    const float* __restrict__ reP, const float* __restrict__ imP,
    const float* __restrict__ u, const float* __restrict__ W,
    float* __restrict__ y) {
  __shared__ float At[32][132];
  __shared__ float Bt[32][132];
  const int t = threadIdx.x;
  const int m0 = blockIdx.x * 128;
  const int tm = t & 15, tn = t >> 4;
  const int lr = t >> 3;   // 0..31
  const int kq = t & 7;    // 0..7
  const int b = m0 >> 13;
  const int l0 = m0 & (SEQLEN - 1);
  float acc[8][8] = {};
  float4 va[4], vb[4];

  auto loadT = [&](int kt, int p, float4& a, float4& bo) {
    int mrow = p * 32 + lr;
    int f = kt * 32 + kq * 4;
    if (kt < 8) {
      size_t row = ((size_t)b * SROWB + l0 + mrow) * (size_t)RS;
      if (ES == 1) a = *(const float4*)(reP + row + f);
      else { const float* pp = reP + row + (size_t)f * 2;
             a = make_float4(pp[0], pp[2], pp[4], pp[6]); }
    } else if (kt < 16) {
      size_t row = ((size_t)b * SROWB + l0 + mrow) * (size_t)RS;
      int g = f - 256;
      if (ES == 1) a = *(const float4*)(imP + row + g);
      else { const float* pp = imP + row + (size_t)g * 2;
             a = make_float4(pp[0], pp[2], pp[4], pp[6]); }
    } else {
      a = *(const float4*)(u + ((size_t)b * SEQLEN + l0 + mrow) * H_IN + (f - 512));
    }
    bo = *(const float4*)(W + (size_t)mrow * 640 + f);
  };
#pragma unroll
  for (int p = 0; p < 4; p++) loadT(0, p, va[p], vb[p]);

  const int NT = 640 / 32;  // 20
  for (int kt = 0; kt < NT; kt++) {
#pragma unroll
    for (int p = 0; p < 4; p++) {
      int row = p * 32 + lr;
      At[kq * 4 + 0][row] = va[p].x; At[kq * 4 + 1][row] = va[p].y;
      At[kq * 4 + 2][row] = va[p].z; At[kq * 4 + 3][row] = va[p].w;
      Bt[kq * 4 + 0][row] = vb[p].x; Bt[kq * 4 + 1][row] = vb[p].y;
      Bt[kq * 4 + 2][row] = vb[p].z; Bt[kq * 4 + 3][row] = vb[p].w;
    }
    __syncthreads();
    if (kt + 1 < NT) {
#pragma unroll
      for (int p = 0; p < 4; p++) loadT(kt + 1, p, va[p], vb[p]);
    }
#pragma unroll 4
    for (int k = 0; k < 32; k++) {
      float4 a0 = *(const float4*)&At[k][tm * 4];
      float4 a1 = *(const float4*)&At[k][tm * 4 + 64];
      float4 b0 = *(const float4*)&Bt[k][tn * 4];
      float4 b1 = *(const float4*)&Bt[k][tn * 4 + 64];
      float ar[8] = {a0.x, a0.y, a0.z, a0.w, a1.x, a1.y, a1.z, a1.w};
      float br[8] = {b0.x, b0.y, b0.z, b0.w, b1.x, b1.y, b1.z, b1.w};
#pragma unroll
      for (int i = 0; i < 8; i++)
#pragma unroll
        for (int j = 0; j < 8; j++) acc[i][j] = fmaf(ar[i], br[j], acc[i][j]);
    }
    __syncthreads();
  }
#pragma unroll
  for (int i = 0; i < 8; i++) {
    int mrow = tm * 4 + (i & 3) + (i >> 2) * 64;
    float* out = y + (size_t)(m0 + mrow) * H_OUT + tn * 4;
    *(float4*)(out) = make_float4(acc[i][0], acc[i][1], acc[i][2], acc[i][3]);
    *(float4*)(out + 64) = make_float4(acc[i][4], acc[i][5], acc[i][6], acc[i][7]);
  }
}

// ---------------------------------------------------------------------------
// Scans (unchanged from passing round-1 version)
// ---------------------------------------------------------------------------
__global__ __launch_bounds__(256) void scanA(
    const float* __restrict__ reP, const float* __restrict__ imP, int es, int rs,
    const float* __restrict__ lamRe, const float* __restrict__ lamIm,
    float* __restrict__ carries) {
  const int blk = blockIdx.x;
  const int b = blk >> 7, c = blk & (NCH - 1);
  const int n = threadIdx.x;
  const float lr = lamRe[n], li = lamIm[n];
  float xr = 0.f, xi = 0.f;
  size_t off = ((size_t)b * SROWB + (size_t)c * CL + 1) * rs + (size_t)n * es;
  const float* pr = reP + off;
  const float* pi = imP + off;
#pragma unroll 4
  for (int t = 0; t < CL; t++) {
    float br = *pr, bi = *pi;
    float nr = fmaf(lr, xr, fmaf(-li, xi, br));
    float ni = fmaf(lr, xi, fmaf(li, xr, bi));
    xr = nr; xi = ni;
    pr += rs; pi += rs;
  }
  size_t ci = ((size_t)blk * NS + n) * 2;
  carries[ci] = xr; carries[ci + 1] = xi;
}

__global__ __launch_bounds__(256) void scanB(
    const float* __restrict__ carries, const float* __restrict__ lamPRe,
    const float* __restrict__ lamPIm, float* __restrict__ starts) {
  const int id = blockIdx.x * 256 + threadIdx.x;  // 0..2047
  const int b = id >> 8, n = id & (NS - 1);
  const float lr = lamPRe[n], li = lamPIm[n];
  float xr = 0.f, xi = 0.f;
  for (int c = 0; c < NCH; c++) {
    size_t idx = (((size_t)b * NCH + c) * NS + n) * 2;
    starts[idx] = xr; starts[idx + 1] = xi;
    float cr = carries[idx], ci = carries[idx + 1];
    float nr = fmaf(lr, xr, fmaf(-li, xi, cr));
    float ni = fmaf(lr, xi, fmaf(li, xr, ci));
    xr = nr; xi = ni;
  }
}

__global__ __launch_bounds__(256) void scanC(
    float* __restrict__ reP, float* __restrict__ imP, int es, int rs,
    const float* __restrict__ lamRe, const float* __restrict__ lamIm,
    const float* __restrict__ starts) {
  const int blk = blockIdx.x;
  const int b = blk >> 7, c = blk & (NCH - 1);
  const int n = threadIdx.x;
  const float lr = lamRe[n], li = lamIm[n];
  size_t sidx = (((size_t)b * NCH + c) * NS + n) * 2;
  float xr = starts[sidx], xi = starts[sidx + 1];
  if (c == 0) {
    size_t o0 = ((size_t)b * SROWB) * rs + (size_t)n * es;
    reP[o0] = 0.f; imP[o0] = 0.f;
  }
  size_t off = ((size_t)b * SROWB + (size_t)c * CL + 1) * rs + (size_t)n * es;
  float* pr = reP + off;
  float* pi = imP + off;
#pragma unroll 4
  for (int t = 0; t < CL; t++) {
    float br = *pr, bi = *pi;
    float nr = fmaf(lr, xr, fmaf(-li, xi, br));
    float ni = fmaf(lr, xi, fmaf(li, xr, bi));
    xr = nr; xi = ni;
    *pr = xr; *pi = xi;
    pr += rs; pi += rs;
  }
}

// ---------------------------------------------------------------------------
extern "C" void kernel_launch(void* const* d_in, const int* in_sizes, int n_in,
                              void* d_out, int out_size, void* d_ws, size_t ws_size,
                              hipStream_t stream) {
  const float* u         = (const float*)d_in[0];
  const float* nu_log    = (const float*)d_in[1];
  const float* theta_log = (const float*)d_in[2];
  const float* gamma_log = (const float*)d_in[3];
  const float* Bp_re     = (const float*)d_in[4];
  const float* Bp_im     = (const float*)d_in[5];
  const float* C_re      = (const float*)d_in[6];
  const float* C_im      = (const float*)d_in[7];
  const float* D         = (const float*)d_in[8];

  float* y  = (float*)d_out;
  float* ws = (float*)d_ws;

  float* Bfi    = ws;                  // 512*128 = 65536
  float* W      = Bfi + 512 * 128;     // 128*640 = 81920
  float* lamRe  = W + 128 * 640;       // 256
  float* lamIm  = lamRe + NS;
  float* lamPRe = lamIm + NS;
  float* lamPIm = lamPRe + NS;
  float* wsFree = lamPIm + NS;
  const size_t smallWsFloats = 148480;

  // carries/starts live in the y region of d_out (y written last; no hazard).
  float* carries = y;                                   // 524288 floats
  float* starts  = y + (size_t)BATCH * NCH * NS * 2;    // 524288 floats

  const size_t stateFloats = (size_t)BATCH * SROWB * NS;  // 16,779,264
  float *reP, *imP;
  int es, rs;
  size_t needWsBytes;
  bool modeA;
  if (out_size >= (int)(Y_FLOATS + 2 * stateFloats)) {
    modeA = false;
    reP = y + Y_FLOATS; imP = reP + 1; es = 2; rs = 512;
    needWsBytes = smallWsFloats * 4;
  } else if (out_size >= (int)(Y_FLOATS + stateFloats)) {
    modeA = true;
    reP = y + Y_FLOATS; imP = wsFree; es = 1; rs = 256;
    needWsBytes = (smallWsFloats + stateFloats) * 4;
  } else {
    return;
  }
  if (ws_size < needWsBytes) return;

  setup_small<<<1, 256, 0, stream>>>(nu_log, theta_log, gamma_log, Bp_re, Bp_im,
                                     Bfi, lamRe, lamIm, lamPRe, lamPIm);
  setup_W<<<(H_OUT * 640 + 255) / 256, 256, 0, stream>>>(C_re, C_im, D, W);
  if (modeA) {
    gemm_bu_k<1, 256><<<dim3(M_TOT / 128, 4), 256, 0, stream>>>(u, Bfi, reP, imP);
  } else {
    gemm_bu_k<2, 512><<<dim3(M_TOT / 128, 4), 256, 0, stream>>>(u, Bfi, reP, imP);
  }
  scanA<<<BATCH * NCH, 256, 0, stream>>>(reP, imP, es, rs, lamRe, lamIm, carries);
  scanB<<<BATCH, 256, 0, stream>>>(carries, lamPRe, lamPIm, starts);
  scanC<<<BATCH * NCH, 256, 0, stream>>>(reP, imP, es, rs, lamRe, lamIm, starts);
  if (modeA) {
    gemm_y_k<1, 256><<<M_TOT / 128, 256, 0, stream>>>(reP, imP, u, W, y);
  } else {
    gemm_y_k<2, 512><<<M_TOT / 128, 256, 0, stream>>>(reP, imP, u, W, y);
  }
}

// Round 4
// 327.449 us; speedup vs baseline: 3.1927x; 1.4023x over previous
//
#include <hip/hip_runtime.h>
#include <hip/hip_bf16.h>

// Problem constants
#define BATCH 8
#define SEQLEN 8192
#define H_IN 128
#define H_OUT 128
#define NS 256
#define M_TOT (BATCH * SEQLEN)          // 65536
#define CL 64
#define NCH (SEQLEN / CL)                // 128
#define Y_FLOATS ((size_t)BATCH * SEQLEN * H_OUT)   // 8388608
#define SROWB (SEQLEN + 1)               // 8193 state rows per batch

// Mode A (HW-confirmed): d_out = [y f32 | Re(states) f32]; Im(states) in ws.
// State element (b,l,n): reP[(b*8193+l)*256 + n], imP[same].

typedef __bf16 bf16x8 __attribute__((ext_vector_type(8)));
typedef __bf16 bf16x4 __attribute__((ext_vector_type(4)));
typedef float f32x4 __attribute__((ext_vector_type(4)));

// XOR swizzle within a 128-byte LDS row (8 x 16B slots)
__device__ __forceinline__ int swzoff(int row, int kbyte) {
  return row * 128 + (kbyte ^ ((row & 7) << 4));
}

__device__ __forceinline__ void split4(float x, float y2, float z, float w,
                                       bf16x4& h, bf16x4& l) {
  h[0] = (__bf16)x; l[0] = (__bf16)(x - (float)h[0]);
  h[1] = (__bf16)y2; l[1] = (__bf16)(y2 - (float)h[1]);
  h[2] = (__bf16)z; l[2] = (__bf16)(z - (float)h[2]);
  h[3] = (__bf16)w; l[3] = (__bf16)(w - (float)h[3]);
}

// ---------------------------------------------------------------------------
// setup_small: lambda tables + split Bfi (rows c: even=gamma*Bp_re, odd=gamma*Bp_im)
// ---------------------------------------------------------------------------
__global__ __launch_bounds__(256) void setup_small(
    const float* __restrict__ nu_log, const float* __restrict__ theta_log,
    const float* __restrict__ gamma_log,
    const float* __restrict__ Bp_re, const float* __restrict__ Bp_im,
    __bf16* __restrict__ Bfi_h, __bf16* __restrict__ Bfi_l,
    float* __restrict__ lamRe, float* __restrict__ lamIm,
    float* __restrict__ lamPRe, float* __restrict__ lamPIm) {
  const int t = threadIdx.x;  // 0..255 = state n
  float e  = expf(nu_log[t]);
  float th = expf(theta_log[t]);
  float r  = expf(-e);
  lamRe[t] = r * cosf(th);
  lamIm[t] = r * sinf(th);
  float rP  = expf(-(float)CL * e);
  float thP = (float)CL * th;
  lamPRe[t] = rP * cosf(thP);
  lamPIm[t] = rP * sinf(thP);
  float g = expf(gamma_log[t]);
  const float4* br = (const float4*)(Bp_re + (size_t)t * H_IN);
  const float4* bi = (const float4*)(Bp_im + (size_t)t * H_IN);
#pragma unroll 4
  for (int h = 0; h < H_IN / 4; h++) {
    float4 a = br[h], b = bi[h];
    bf16x4 hh, ll;
    split4(g * a.x, g * a.y, g * a.z, g * a.w, hh, ll);
    *(bf16x4*)(Bfi_h + (size_t)(2 * t) * H_IN + h * 4) = hh;
    *(bf16x4*)(Bfi_l + (size_t)(2 * t) * H_IN + h * 4) = ll;
    split4(g * b.x, g * b.y, g * b.z, g * b.w, hh, ll);
    *(bf16x4*)(Bfi_h + (size_t)(2 * t + 1) * H_IN + h * 4) = hh;
    *(bf16x4*)(Bfi_l + (size_t)(2 * t + 1) * H_IN + h * 4) = ll;
  }
}

// setup_W: W (128 x 640) = [C_re | -C_im | D], split into bf16 hi/lo
__global__ __launch_bounds__(256) void setup_W(
    const float* __restrict__ C_re, const float* __restrict__ C_im,
    const float* __restrict__ D,
    __bf16* __restrict__ W_h, __bf16* __restrict__ W_l) {
  int i = blockIdx.x * 256 + threadIdx.x;
  if (i >= H_OUT * 640) return;
  int o = i / 640, k = i - o * 640;
  float v;
  if (k < NS)          v = C_re[(size_t)o * NS + k];
  else if (k < 2 * NS) v = -C_im[(size_t)o * NS + (k - NS)];
  else                 v = D[(size_t)o * H_IN + (k - 2 * NS)];
  __bf16 h = (__bf16)v;
  W_h[i] = h;
  W_l[i] = (__bf16)(v - (float)h);
}

// ---------------------------------------------------------------------------
// gemm_bu_mfma: Bu[m][c] = sum_h u[m][h]*Bfi[c][h]  (c 0..511, even=re odd=im)
// bf16x3 split MFMA, BM=128 BN=128 BK=64, 4 waves in 2x2, 16x16x32 frags.
// ---------------------------------------------------------------------------
__global__ __launch_bounds__(256) void gemm_bu_mfma(
    const float* __restrict__ u,
    const __bf16* __restrict__ Bfi_h, const __bf16* __restrict__ Bfi_l,
    float* __restrict__ reP, float* __restrict__ imP) {
  __shared__ char AhS[128 * 128];  // 128 rows x 64 bf16 (128 B)
  __shared__ char AlS[128 * 128];
  __shared__ char BhS[128 * 128];
  __shared__ char BlS[128 * 128];
  const int t = threadIdx.x;
  const int lane = t & 63, wid = t >> 6;
  const int wm = wid >> 1, wn = wid & 1;
  const int n0 = blockIdx.x * 128;
  const int m0 = blockIdx.y * 128;
  const int srow = t >> 1;              // staging row 0..127
  const int skb = (t & 1) * 32;         // staging k base (elements)
  f32x4 acc[4][4] = {};

  for (int kt = 0; kt < 2; kt++) {      // K = 128 = 2 tiles of 64
    // stage A (u, f32 -> hi/lo bf16)
    {
      const float* src = u + (size_t)(m0 + srow) * H_IN + kt * 64 + skb;
#pragma unroll
      for (int q = 0; q < 8; q++) {
        float4 v = *(const float4*)(src + q * 4);
        bf16x4 h4, l4;
        split4(v.x, v.y, v.z, v.w, h4, l4);
        int off = swzoff(srow, (skb + q * 4) * 2);
        *(bf16x4*)(AhS + off) = h4;
        *(bf16x4*)(AlS + off) = l4;
      }
    }
    // stage B (pre-split weights)
    {
      const __bf16* sh = Bfi_h + (size_t)(n0 + srow) * H_IN + kt * 64 + skb;
      const __bf16* sl = Bfi_l + (size_t)(n0 + srow) * H_IN + kt * 64 + skb;
#pragma unroll
      for (int q = 0; q < 4; q++) {
        int off = swzoff(srow, (skb + q * 8) * 2);
        *(bf16x8*)(BhS + off) = *(const bf16x8*)(sh + q * 8);
        *(bf16x8*)(BlS + off) = *(const bf16x8*)(sl + q * 8);
      }
    }
    __syncthreads();
#pragma unroll
    for (int ks = 0; ks < 2; ks++) {
      bf16x8 ah[4], al[4], bh[4], bl[4];
      const int kby = ks * 64 + (lane >> 4) * 16;
#pragma unroll
      for (int mt = 0; mt < 4; mt++) {
        int r = wm * 64 + mt * 16 + (lane & 15);
        int off = swzoff(r, kby);
        ah[mt] = *(const bf16x8*)(AhS + off);
        al[mt] = *(const bf16x8*)(AlS + off);
      }
#pragma unroll
      for (int nt = 0; nt < 4; nt++) {
        int r = wn * 64 + nt * 16 + (lane & 15);
        int off = swzoff(r, kby);
        bh[nt] = *(const bf16x8*)(BhS + off);
        bl[nt] = *(const bf16x8*)(BlS + off);
      }
#pragma unroll
      for (int mt = 0; mt < 4; mt++)
#pragma unroll
        for (int nt = 0; nt < 4; nt++) {
          acc[mt][nt] = __builtin_amdgcn_mfma_f32_16x16x32_bf16(
              ah[mt], bh[nt], acc[mt][nt], 0, 0, 0);
          acc[mt][nt] = __builtin_amdgcn_mfma_f32_16x16x32_bf16(
              ah[mt], bl[nt], acc[mt][nt], 0, 0, 0);
          acc[mt][nt] = __builtin_amdgcn_mfma_f32_16x16x32_bf16(
              al[mt], bh[nt], acc[mt][nt], 0, 0, 0);
        }
    }
    __syncthreads();
  }
  // epilogue: D[row][col], col = lane&15 group, row = (lane>>4)*4 + reg
  const int b = m0 >> 13;
  const int l1 = (m0 & (SEQLEN - 1)) + 1;
#pragma unroll
  for (int mt = 0; mt < 4; mt++)
#pragma unroll
    for (int nt = 0; nt < 4; nt++) {
      int c = n0 + wn * 64 + nt * 16 + (lane & 15);
      float* dst = (c & 1) ? imP : reP;
      size_t cc = (size_t)(c >> 1);
#pragma unroll
      for (int r = 0; r < 4; r++) {
        int mr = wm * 64 + mt * 16 + ((lane >> 4) << 2) + r;
        dst[((size_t)b * SROWB + l1 + mr) * NS + cc] = acc[mt][nt][r];
      }
    }
}

// ---------------------------------------------------------------------------
// gemm_y_mfma: y[m][o] = sum_{k<640} Afull[m][k] * W[o][k]
//   Afull = [Re(pre) (256) | Im(pre) (256) | u (128)]; pre-state row = l.
// bf16x3 split MFMA, BM=128 BN=128(=H_OUT) BK=64, 10 k-tiles.
// ---------------------------------------------------------------------------
__global__ __launch_bounds__(256) void gemm_y_mfma(
    const float* __restrict__ reP, const float* __restrict__ imP,
    const float* __restrict__ u,
    const __bf16* __restrict__ W_h, const __bf16* __restrict__ W_l,
    float* __restrict__ y) {
  __shared__ char AhS[128 * 128];
  __shared__ char AlS[128 * 128];
  __shared__ char BhS[128 * 128];
  __shared__ char BlS[128 * 128];
  const int t = threadIdx.x;
  const int lane = t & 63, wid = t >> 6;
  const int wm = wid >> 1, wn = wid & 1;
  const int m0 = blockIdx.x * 128;
  const int b = m0 >> 13;
  const int l0 = m0 & (SEQLEN - 1);
  const int srow = t >> 1;
  const int skb = (t & 1) * 32;
  f32x4 acc[4][4] = {};

  for (int kt = 0; kt < 10; kt++) {
    // stage A: split f32 source -> hi/lo
    {
      const float* src;
      if (kt < 4)
        src = reP + ((size_t)b * SROWB + l0 + srow) * NS + kt * 64 + skb;
      else if (kt < 8)
        src = imP + ((size_t)b * SROWB + l0 + srow) * NS + (kt - 4) * 64 + skb;
      else
        src = u + ((size_t)b * SEQLEN + l0 + srow) * H_IN + (kt - 8) * 64 + skb;
#pragma unroll
      for (int q = 0; q < 8; q++) {
        float4 v = *(const float4*)(src + q * 4);
        bf16x4 h4, l4;
        split4(v.x, v.y, v.z, v.w, h4, l4);
        int off = swzoff(srow, (skb + q * 4) * 2);
        *(bf16x4*)(AhS + off) = h4;
        *(bf16x4*)(AlS + off) = l4;
      }
    }
    // stage B (pre-split W)
    {
      const __bf16* sh = W_h + (size_t)srow * 640 + kt * 64 + skb;
      const __bf16* sl = W_l + (size_t)srow * 640 + kt * 64 + skb;
#pragma unroll
      for (int q = 0; q < 4; q++) {
        int off = swzoff(srow, (skb + q * 8) * 2);
        *(bf16x8*)(BhS + off) = *(const bf16x8*)(sh + q * 8);
        *(bf16x8*)(BlS + off) = *(const bf16x8*)(sl + q * 8);
      }
    }
    __syncthreads();
#pragma unroll
    for (int ks = 0; ks < 2; ks++) {
      bf16x8 ah[4], al[4], bh[4], bl[4];
      const int kby = ks * 64 + (lane >> 4) * 16;
#pragma unroll
      for (int mt = 0; mt < 4; mt++) {
        int r = wm * 64 + mt * 16 + (lane & 15);
        int off = swzoff(r, kby);
        ah[mt] = *(const bf16x8*)(AhS + off);
        al[mt] = *(const bf16x8*)(AlS + off);
      }
#pragma unroll
      for (int nt = 0; nt < 4; nt++) {
        int r = wn * 64 + nt * 16 + (lane & 15);
        int off = swzoff(r, kby);
        bh[nt] = *(const bf16x8*)(BhS + off);
        bl[nt] = *(const bf16x8*)(BlS + off);
      }
#pragma unroll
      for (int mt = 0; mt < 4; mt++)
#pragma unroll
        for (int nt = 0; nt < 4; nt++) {
          acc[mt][nt] = __builtin_amdgcn_mfma_f32_16x16x32_bf16(
              ah[mt], bh[nt], acc[mt][nt], 0, 0, 0);
          acc[mt][nt] = __builtin_amdgcn_mfma_f32_16x16x32_bf16(
              ah[mt], bl[nt], acc[mt][nt], 0, 0, 0);
          acc[mt][nt] = __builtin_amdgcn_mfma_f32_16x16x32_bf16(
              al[mt], bh[nt], acc[mt][nt], 0, 0, 0);
        }
    }
    __syncthreads();
  }
#pragma unroll
  for (int mt = 0; mt < 4; mt++)
#pragma unroll
    for (int nt = 0; nt < 4; nt++) {
      int col = wn * 64 + nt * 16 + (lane & 15);
#pragma unroll
      for (int r = 0; r < 4; r++) {
        int mr = wm * 64 + mt * 16 + ((lane >> 4) << 2) + r;
        y[(size_t)(m0 + mr) * H_OUT + col] = acc[mt][nt][r];
      }
    }
}

// ---------------------------------------------------------------------------
// Scans (unchanged, mode A: es=1 rs=256)
// ---------------------------------------------------------------------------
__global__ __launch_bounds__(256) void scanA(
    const float* __restrict__ reP, const float* __restrict__ imP,
    const float* __restrict__ lamRe, const float* __restrict__ lamIm,
    float* __restrict__ carries) {
  const int blk = blockIdx.x;
  const int b = blk >> 7, c = blk & (NCH - 1);
  const int n = threadIdx.x;
  const float lr = lamRe[n], li = lamIm[n];
  float xr = 0.f, xi = 0.f;
  size_t off = ((size_t)b * SROWB + (size_t)c * CL + 1) * NS + n;
  const float* pr = reP + off;
  const float* pi = imP + off;
#pragma unroll 4
  for (int t = 0; t < CL; t++) {
    float br = *pr, bi = *pi;
    float nr = fmaf(lr, xr, fmaf(-li, xi, br));
    float ni = fmaf(lr, xi, fmaf(li, xr, bi));
    xr = nr; xi = ni;
    pr += NS; pi += NS;
  }
  size_t ci = ((size_t)blk * NS + n) * 2;
  carries[ci] = xr; carries[ci + 1] = xi;
}

__global__ __launch_bounds__(256) void scanB(
    const float* __restrict__ carries, const float* __restrict__ lamPRe,
    const float* __restrict__ lamPIm, float* __restrict__ starts) {
  const int id = blockIdx.x * 256 + threadIdx.x;  // 0..2047
  const int b = id >> 8, n = id & (NS - 1);
  const float lr = lamPRe[n], li = lamPIm[n];
  float xr = 0.f, xi = 0.f;
  for (int c = 0; c < NCH; c++) {
    size_t idx = (((size_t)b * NCH + c) * NS + n) * 2;
    starts[idx] = xr; starts[idx + 1] = xi;
    float cr = carries[idx], ci = carries[idx + 1];
    float nr = fmaf(lr, xr, fmaf(-li, xi, cr));
    float ni = fmaf(lr, xi, fmaf(li, xr, ci));
    xr = nr; xi = ni;
  }
}

__global__ __launch_bounds__(256) void scanC(
    float* __restrict__ reP, float* __restrict__ imP,
    const float* __restrict__ lamRe, const float* __restrict__ lamIm,
    const float* __restrict__ starts) {
  const int blk = blockIdx.x;
  const int b = blk >> 7, c = blk & (NCH - 1);
  const int n = threadIdx.x;
  const float lr = lamRe[n], li = lamIm[n];
  size_t sidx = (((size_t)b * NCH + c) * NS + n) * 2;
  float xr = starts[sidx], xi = starts[sidx + 1];
  if (c == 0) {
    size_t o0 = ((size_t)b * SROWB) * NS + n;
    reP[o0] = 0.f; imP[o0] = 0.f;
  }
  size_t off = ((size_t)b * SROWB + (size_t)c * CL + 1) * NS + n;
  float* pr = reP + off;
  float* pi = imP + off;
#pragma unroll 4
  for (int t = 0; t < CL; t++) {
    float br = *pr, bi = *pi;
    float nr = fmaf(lr, xr, fmaf(-li, xi, br));
    float ni = fmaf(lr, xi, fmaf(li, xr, bi));
    xr = nr; xi = ni;
    *pr = xr; *pi = xi;
    pr += NS; pi += NS;
  }
}

// ---------------------------------------------------------------------------
extern "C" void kernel_launch(void* const* d_in, const int* in_sizes, int n_in,
                              void* d_out, int out_size, void* d_ws, size_t ws_size,
                              hipStream_t stream) {
  const float* u         = (const float*)d_in[0];
  const float* nu_log    = (const float*)d_in[1];
  const float* theta_log = (const float*)d_in[2];
  const float* gamma_log = (const float*)d_in[3];
  const float* Bp_re     = (const float*)d_in[4];
  const float* Bp_im     = (const float*)d_in[5];
  const float* C_re      = (const float*)d_in[6];
  const float* C_im      = (const float*)d_in[7];
  const float* D         = (const float*)d_in[8];

  float* y = (float*)d_out;
  char* wsb = (char*)d_ws;

  // ws layout (bytes)
  float*  lamRe  = (float*)(wsb + 0);
  float*  lamIm  = lamRe + NS;
  float*  lamPRe = lamIm + NS;
  float*  lamPIm = lamPRe + NS;                       // end 4096
  __bf16* Bfi_h  = (__bf16*)(wsb + 4096);             // 131072 B
  __bf16* Bfi_l  = (__bf16*)(wsb + 4096 + 131072);    // 131072 B
  __bf16* W_h    = (__bf16*)(wsb + 4096 + 262144);    // 163840 B
  __bf16* W_l    = (__bf16*)(wsb + 4096 + 262144 + 163840);
  float*  imP    = (float*)(wsb + 593920);

  const size_t stateFloats = (size_t)BATCH * SROWB * NS;  // 16,779,264
  // mode A required: d_out = [y | Re(states)]
  if (out_size < (int)(Y_FLOATS + stateFloats) ||
      out_size >= (int)(Y_FLOATS + 2 * stateFloats))
    return;
  if (ws_size < 593920 + stateFloats * 4) return;
  float* reP = y + Y_FLOATS;

  // carries/starts in the y region of d_out (y written last; no hazard).
  float* carries = y;                                   // 524288 floats
  float* starts  = y + (size_t)BATCH * NCH * NS * 2;    // 524288 floats

  setup_small<<<1, 256, 0, stream>>>(nu_log, theta_log, gamma_log, Bp_re, Bp_im,
                                     Bfi_h, Bfi_l, lamRe, lamIm, lamPRe, lamPIm);
  setup_W<<<(H_OUT * 640 + 255) / 256, 256, 0, stream>>>(C_re, C_im, D, W_h, W_l);
  gemm_bu_mfma<<<dim3(4, M_TOT / 128), 256, 0, stream>>>(u, Bfi_h, Bfi_l, reP, imP);
  scanA<<<BATCH * NCH, 256, 0, stream>>>(reP, imP, lamRe, lamIm, carries);
  scanB<<<BATCH, 256, 0, stream>>>(carries, lamPRe, lamPIm, starts);
  scanC<<<BATCH * NCH, 256, 0, stream>>>(reP, imP, lamRe, lamIm, starts);
  gemm_y_mfma<<<M_TOT / 128, 256, 0, stream>>>(reP, imP, u, W_h, W_l, y);
}

// Round 8
// 317.940 us; speedup vs baseline: 3.2882x; 1.0299x over previous
//
#include <hip/hip_runtime.h>
#include <hip/hip_bf16.h>

// Problem constants
#define BATCH 8
#define SEQLEN 8192
#define H_IN 128
#define H_OUT 128
#define NS 256
#define M_TOT (BATCH * SEQLEN)          // 65536
#define CL 64
#define NCH (SEQLEN / CL)                // 128
#define Y_FLOATS ((size_t)BATCH * SEQLEN * H_OUT)   // 8388608
#define SROWB (SEQLEN + 1)               // 8193 state rows per batch

// Mode A (HW-confirmed): d_out = [y f32 | Re(states) f32].
// reP holds Bu.re (rows l+1) until scan_gemm_y overwrites it in place with
// Re(states). imP (ws) holds Bu.im only; Im(states) never hits HBM.

typedef __bf16 bf16x8 __attribute__((ext_vector_type(8)));
typedef __bf16 bf16x4 __attribute__((ext_vector_type(4)));
typedef float f32x4 __attribute__((ext_vector_type(4)));
typedef unsigned int u32;

__device__ __forceinline__ int swzoff(int row, int kbyte) {
  return row * 128 + (kbyte ^ ((row & 7) << 4));
}

__device__ __forceinline__ void split4(float x, float y2, float z, float w,
                                       bf16x4& h, bf16x4& l) {
  h[0] = (__bf16)x; l[0] = (__bf16)(x - (float)h[0]);
  h[1] = (__bf16)y2; l[1] = (__bf16)(y2 - (float)h[1]);
  h[2] = (__bf16)z; l[2] = (__bf16)(z - (float)h[2]);
  h[3] = (__bf16)w; l[3] = (__bf16)(w - (float)h[3]);
}

__device__ __forceinline__ u32 bfpack(__bf16 a, __bf16 b) {
  union { unsigned short s; __bf16 h; } ua, ub;
  ua.h = a; ub.h = b;
  return (u32)ua.s | ((u32)ub.s << 16);
}

__device__ __forceinline__ bf16x8 cat8(bf16x4 a, bf16x4 b) {
  bf16x8 r;
  r[0] = a[0]; r[1] = a[1]; r[2] = a[2]; r[3] = a[3];
  r[4] = b[0]; r[5] = b[1]; r[6] = b[2]; r[7] = b[3];
  return r;
}

// ---------------------------------------------------------------------------
// setup_small: lambda tables + split Bfi (rows c: even=g*Bp_re, odd=g*Bp_im)
// ---------------------------------------------------------------------------
__global__ __launch_bounds__(256) void setup_small(
    const float* __restrict__ nu_log, const float* __restrict__ theta_log,
    const float* __restrict__ gamma_log,
    const float* __restrict__ Bp_re, const float* __restrict__ Bp_im,
    __bf16* __restrict__ Bfi_h, __bf16* __restrict__ Bfi_l,
    float* __restrict__ lamRe, float* __restrict__ lamIm,
    float* __restrict__ lamPRe, float* __restrict__ lamPIm) {
  const int t = threadIdx.x;  // 0..255 = state n
  float e  = expf(nu_log[t]);
  float th = expf(theta_log[t]);
  float r  = expf(-e);
  lamRe[t] = r * cosf(th);
  lamIm[t] = r * sinf(th);
  float rP  = expf(-(float)CL * e);
  float thP = (float)CL * th;
  lamPRe[t] = rP * cosf(thP);
  lamPIm[t] = rP * sinf(thP);
  float g = expf(gamma_log[t]);
  const float4* br = (const float4*)(Bp_re + (size_t)t * H_IN);
  const float4* bi = (const float4*)(Bp_im + (size_t)t * H_IN);
#pragma unroll 4
  for (int h = 0; h < H_IN / 4; h++) {
    float4 a = br[h], b = bi[h];
    bf16x4 hh, ll;
    split4(g * a.x, g * a.y, g * a.z, g * a.w, hh, ll);
    *(bf16x4*)(Bfi_h + (size_t)(2 * t) * H_IN + h * 4) = hh;
    *(bf16x4*)(Bfi_l + (size_t)(2 * t) * H_IN + h * 4) = ll;
    split4(g * b.x, g * b.y, g * b.z, g * b.w, hh, ll);
    *(bf16x4*)(Bfi_h + (size_t)(2 * t + 1) * H_IN + h * 4) = hh;
    *(bf16x4*)(Bfi_l + (size_t)(2 * t + 1) * H_IN + h * 4) = ll;
  }
}

// ---------------------------------------------------------------------------
// setup_Wfrag: fragment-major W tables for the fused y-GEMM.
// Logical W[o][k]: k=2n -> C_re[o][n], k=2n+1 -> -C_im[o][n], k>=512 -> D[o][k-512]
// Layout: Wf[((k32*8 + ntg)*64 + lane)*8 + j] = W[ntg*16+(lane&15)][k32*32+(lane>>4)*8+j]
// ---------------------------------------------------------------------------
__global__ __launch_bounds__(256) void setup_Wfrag(
    const float* __restrict__ C_re, const float* __restrict__ C_im,
    const float* __restrict__ D,
    __bf16* __restrict__ Wf_h, __bf16* __restrict__ Wf_l) {
  int i = blockIdx.x * 256 + threadIdx.x;
  if (i >= 20 * 8 * 64 * 8) return;
  int j    = i & 7;
  int lane = (i >> 3) & 63;
  int ntg  = (i >> 9) & 7;
  int k32  = i >> 12;                        // 0..19
  int o = ntg * 16 + (lane & 15);
  int k = k32 * 32 + ((lane >> 4) << 3) + j;
  float v;
  if (k < 512) {
    int n = k >> 1;
    v = (k & 1) ? -C_im[(size_t)o * NS + n] : C_re[(size_t)o * NS + n];
  } else {
    v = D[(size_t)o * H_IN + (k - 512)];
  }
  __bf16 h = (__bf16)v;
  Wf_h[i] = h;
  Wf_l[i] = (__bf16)(v - (float)h);
}

// ---------------------------------------------------------------------------
// gemm_bu_mfma: Bu tile (128 rows x 128 f32 cols) -> global Bu.re/.im.
// Round-4-proven epilogue (no fused scan). XCD-swizzled grid kept (bijective).
// ---------------------------------------------------------------------------
__global__ __launch_bounds__(256) void gemm_bu_mfma(
    const float* __restrict__ u,
    const __bf16* __restrict__ Bfi_h, const __bf16* __restrict__ Bfi_l,
    float* __restrict__ reP, float* __restrict__ imP) {
  __shared__ char smem[65536];
  char* AhS = smem;
  char* AlS = smem + 16384;
  char* BhS = smem + 32768;
  char* BlS = smem + 49152;
  const int t = threadIdx.x;
  const int lane = t & 63, wid = t >> 6;
  const int wm = wid >> 1, wn = wid & 1;
  // XCD swizzle: XCD x (= d%8) covers contiguous orig range [x*256, x*256+255]
  const int d = blockIdx.x;
  const int orig = (d & 7) * 256 + (d >> 3);
  const int n0 = (orig & 3) * 128;
  const int m0 = (orig >> 2) * 128;
  const int srow = t >> 1;
  const int skb = (t & 1) * 32;
  f32x4 acc[4][4] = {};

  for (int kt = 0; kt < 2; kt++) {      // K = 128 = 2 tiles of 64
    {
      const float* src = u + (size_t)(m0 + srow) * H_IN + kt * 64 + skb;
#pragma unroll
      for (int q = 0; q < 8; q++) {
        float4 v = *(const float4*)(src + q * 4);
        bf16x4 h4, l4;
        split4(v.x, v.y, v.z, v.w, h4, l4);
        int off = swzoff(srow, (skb + q * 4) * 2);
        *(bf16x4*)(AhS + off) = h4;
        *(bf16x4*)(AlS + off) = l4;
      }
    }
    {
      const __bf16* sh = Bfi_h + (size_t)(n0 + srow) * H_IN + kt * 64 + skb;
      const __bf16* sl = Bfi_l + (size_t)(n0 + srow) * H_IN + kt * 64 + skb;
#pragma unroll
      for (int q = 0; q < 4; q++) {
        int off = swzoff(srow, (skb + q * 8) * 2);
        *(bf16x8*)(BhS + off) = *(const bf16x8*)(sh + q * 8);
        *(bf16x8*)(BlS + off) = *(const bf16x8*)(sl + q * 8);
      }
    }
    __syncthreads();
#pragma unroll
    for (int ks = 0; ks < 2; ks++) {
      bf16x8 ah[4], al[4], bh[4], bl[4];
      const int kby = ks * 64 + (lane >> 4) * 16;
#pragma unroll
      for (int mt = 0; mt < 4; mt++) {
        int r = wm * 64 + mt * 16 + (lane & 15);
        int off = swzoff(r, kby);
        ah[mt] = *(const bf16x8*)(AhS + off);
        al[mt] = *(const bf16x8*)(AlS + off);
      }
#pragma unroll
      for (int nt = 0; nt < 4; nt++) {
        int r = wn * 64 + nt * 16 + (lane & 15);
        int off = swzoff(r, kby);
        bh[nt] = *(const bf16x8*)(BhS + off);
        bl[nt] = *(const bf16x8*)(BlS + off);
      }
#pragma unroll
      for (int mt = 0; mt < 4; mt++)
#pragma unroll
        for (int nt = 0; nt < 4; nt++) {
          acc[mt][nt] = __builtin_amdgcn_mfma_f32_16x16x32_bf16(
              ah[mt], bh[nt], acc[mt][nt], 0, 0, 0);
          acc[mt][nt] = __builtin_amdgcn_mfma_f32_16x16x32_bf16(
              ah[mt], bl[nt], acc[mt][nt], 0, 0, 0);
          acc[mt][nt] = __builtin_amdgcn_mfma_f32_16x16x32_bf16(
              al[mt], bh[nt], acc[mt][nt], 0, 0, 0);
        }
    }
    __syncthreads();
  }
  // epilogue (round-4 proven): D[row][col], col=lane&15, row=(lane>>4)*4+reg
  const int b = m0 >> 13;
  const int l1 = (m0 & (SEQLEN - 1)) + 1;
#pragma unroll
  for (int mt = 0; mt < 4; mt++)
#pragma unroll
    for (int nt = 0; nt < 4; nt++) {
      int c = n0 + wn * 64 + nt * 16 + (lane & 15);
      float* dst = (c & 1) ? imP : reP;
      size_t cc = (size_t)(c >> 1);
#pragma unroll
      for (int r = 0; r < 4; r++) {
        int mr = wm * 64 + mt * 16 + ((lane >> 4) << 2) + r;
        dst[((size_t)b * SROWB + l1 + mr) * NS + cc] = acc[mt][nt][r];
      }
    }
}

// ---------------------------------------------------------------------------
// scanA (round-4 proven): per-chunk carry from global Bu. Block=(b,chunk).
// ---------------------------------------------------------------------------
__global__ __launch_bounds__(256) void scanA(
    const float* __restrict__ reP, const float* __restrict__ imP,
    const float* __restrict__ lamRe, const float* __restrict__ lamIm,
    float* __restrict__ carries) {
  const int blk = blockIdx.x;
  const int b = blk >> 7, c = blk & (NCH - 1);
  const int n = threadIdx.x;
  const float lr = lamRe[n], li = lamIm[n];
  float xr = 0.f, xi = 0.f;
  size_t off = ((size_t)b * SROWB + (size_t)c * CL + 1) * NS + n;
  const float* pr = reP + off;
  const float* pi = imP + off;
#pragma unroll 4
  for (int t = 0; t < CL; t++) {
    float br = *pr, bi = *pi;
    float nr = fmaf(lr, xr, fmaf(-li, xi, br));
    float ni = fmaf(lr, xi, fmaf(li, xr, bi));
    xr = nr; xi = ni;
    pr += NS; pi += NS;
  }
  size_t ci = ((size_t)blk * NS + n) * 2;
  carries[ci] = xr; carries[ci + 1] = xi;
}

// ---------------------------------------------------------------------------
// scanB: scan carries across chunks per (b,n) chain; overwrites carries IN
// PLACE with the chunk-start states (read carry, then store start).
// ---------------------------------------------------------------------------
__global__ __launch_bounds__(256) void scanB(
    float* __restrict__ carries, const float* __restrict__ lamPRe,
    const float* __restrict__ lamPIm) {
  const int id = blockIdx.x * 256 + threadIdx.x;  // 0..2047
  const int b = id >> 8, n = id & (NS - 1);
  const float lr = lamPRe[n], li = lamPIm[n];
  float xr = 0.f, xi = 0.f;
  for (int c = 0; c < NCH; c++) {
    size_t idx = (((size_t)b * NCH + c) * NS + n) * 2;
    float cr = carries[idx], ci = carries[idx + 1];
    carries[idx] = xr; carries[idx + 1] = xi;   // becomes "starts"
    float nr = fmaf(lr, xr, fmaf(-li, xi, cr));
    float ni = fmaf(lr, xi, fmaf(li, xr, ci));
    xr = nr; xi = ni;
  }
}

// ---------------------------------------------------------------------------
// scan_gemm_y: fused scanC + gemm_y. Block = (chunk c, batch b), 256 thr/4 waves.
// Phase 1: thread n scans its complex state over 64 rows from starts, writes
//   Re(states) in place over Bu.re (global), stores pre-states split bf16
//   hi/lo into LDS (Sh/Sl, 64 rows x 512 cols interleaved re/im, XOR-swizzled).
// Phase 2: y-GEMM M=64 x N=128, K=640 = [states 512 | u 128]. A-frags from LDS
//   (k<512) / global u + reg split; B-frags from fragment-major Wf (L2).
// ---------------------------------------------------------------------------
__global__ __launch_bounds__(256) void scan_gemm_y(
    float* __restrict__ reP, const float* __restrict__ imP,
    const float* __restrict__ u,
    const __bf16* __restrict__ Wf_h, const __bf16* __restrict__ Wf_l,
    const float* __restrict__ lamRe, const float* __restrict__ lamIm,
    const float* __restrict__ starts, float* __restrict__ y) {
  __shared__ __bf16 Sh[64 * 512];   // 64 KiB
  __shared__ __bf16 Sl[64 * 512];   // 64 KiB  (total 128 KiB)
  const int t = threadIdx.x;
  const int c = blockIdx.x;         // chunk 0..127
  const int b = blockIdx.y;
  const int l0 = c * CL;

  // ---- phase 1: scan (all 256 threads, one complex state each) ----
  {
    const int n = t;
    const float lr = lamRe[n], li = lamIm[n];
    size_t sidx = (((size_t)b * NCH + c) * NS + n) * 2;
    float xr = starts[sidx], xi = starts[sidx + 1];
    // store pre-state row 0
    {
      __bf16 hr = (__bf16)xr; __bf16 hi_ = (__bf16)xi;
      __bf16 lr_ = (__bf16)(xr - (float)hr);
      __bf16 li_ = (__bf16)(xi - (float)hi_);
      int idx = (2 * n) ^ 0;  // row 0: no swizzle bits
      *(u32*)&Sh[idx] = bfpack(hr, hi_);
      *(u32*)&Sl[idx] = bfpack(lr_, li_);
    }
    if (c == 0) reP[((size_t)b * SROWB) * NS + n] = 0.f;  // Re row 0 = x0
    float* pr = reP + ((size_t)b * SROWB + l0 + 1) * NS + n;
    const float* pi = imP + ((size_t)b * SROWB + l0 + 1) * NS + n;
    // software-pipelined: groups of 16 rows
    const int PF = 16;
    float brA[PF], biA[PF];
#pragma unroll
    for (int q = 0; q < PF; q++) { brA[q] = pr[q * NS]; biA[q] = pi[q * NS]; }
    for (int g = 0; g < CL / PF; g++) {
      float brN[PF] = {}, biN[PF] = {};   // zero-init: no UB at last group
      if (g + 1 < CL / PF) {
#pragma unroll
        for (int q = 0; q < PF; q++) {
          brN[q] = pr[((g + 1) * PF + q) * NS];
          biN[q] = pi[((g + 1) * PF + q) * NS];
        }
      }
#pragma unroll
      for (int q = 0; q < PF; q++) {
        int tt = g * PF + q;
        float nr = fmaf(lr, xr, fmaf(-li, xi, brA[q]));
        float ni = fmaf(lr, xi, fmaf(li, xr, biA[q]));
        xr = nr; xi = ni;
        pr[tt * NS] = xr;                    // Re(state) in place over Bu.re
        if (tt < CL - 1) {
          int row = tt + 1;
          __bf16 hr = (__bf16)xr; __bf16 hi_ = (__bf16)xi;
          __bf16 lr_ = (__bf16)(xr - (float)hr);
          __bf16 li_ = (__bf16)(xi - (float)hi_);
          int idx = row * 512 + ((2 * n) ^ ((row & 7) << 3));
          *(u32*)&Sh[idx] = bfpack(hr, hi_);
          *(u32*)&Sl[idx] = bfpack(lr_, li_);
        }
      }
#pragma unroll
      for (int q = 0; q < PF; q++) { brA[q] = brN[q]; biA[q] = biN[q]; }
    }
  }
  __syncthreads();

  // ---- phase 2: y-GEMM ----
  const int lane = t & 63, w = t >> 6;   // wave 0..3 -> output cols w*32
  const int arow = lane & 15;
  const int kq = lane >> 4;              // 0..3
  f32x4 acc[4][2] = {};
  for (int k32 = 0; k32 < 20; k32++) {
    bf16x8 ah[4], al[4];
    if (k32 < 16) {
      const int kbase = k32 * 32 + kq * 8;
#pragma unroll
      for (int mt = 0; mt < 4; mt++) {
        int row = mt * 16 + arow;
        int idx = row * 512 + (kbase ^ ((row & 7) << 3));
        ah[mt] = *(const bf16x8*)&Sh[idx];
        al[mt] = *(const bf16x8*)&Sl[idx];
      }
    } else {
      const int kbase = (k32 - 16) * 32 + kq * 8;
#pragma unroll
      for (int mt = 0; mt < 4; mt++) {
        int row = mt * 16 + arow;
        const float* up = u + ((size_t)b * SEQLEN + l0 + row) * H_IN + kbase;
        float4 v0 = *(const float4*)up;
        float4 v1 = *(const float4*)(up + 4);
        bf16x4 h0, l0v, h1, l1v;
        split4(v0.x, v0.y, v0.z, v0.w, h0, l0v);
        split4(v1.x, v1.y, v1.z, v1.w, h1, l1v);
        ah[mt] = cat8(h0, h1);
        al[mt] = cat8(l0v, l1v);
      }
    }
#pragma unroll
    for (int nt = 0; nt < 2; nt++) {
      int ntg = w * 2 + nt;
      size_t wi = (((size_t)k32 * 8 + ntg) * 64 + lane) * 8;
      bf16x8 bh = *(const bf16x8*)&Wf_h[wi];
      bf16x8 bl = *(const bf16x8*)&Wf_l[wi];
#pragma unroll
      for (int mt = 0; mt < 4; mt++) {
        acc[mt][nt] = __builtin_amdgcn_mfma_f32_16x16x32_bf16(
            ah[mt], bh, acc[mt][nt], 0, 0, 0);
        acc[mt][nt] = __builtin_amdgcn_mfma_f32_16x16x32_bf16(
            ah[mt], bl, acc[mt][nt], 0, 0, 0);
        acc[mt][nt] = __builtin_amdgcn_mfma_f32_16x16x32_bf16(
            al[mt], bh, acc[mt][nt], 0, 0, 0);
      }
    }
  }
  // epilogue: y[m][col], col = w*32 + nt*16 + (lane&15), row = mt*16 + kq*4 + r
#pragma unroll
  for (int mt = 0; mt < 4; mt++)
#pragma unroll
    for (int nt = 0; nt < 2; nt++) {
      int col = w * 32 + nt * 16 + (lane & 15);
#pragma unroll
      for (int r = 0; r < 4; r++) {
        int mrow = l0 + mt * 16 + kq * 4 + r;
        y[((size_t)b * SEQLEN + mrow) * H_OUT + col] = acc[mt][nt][r];
      }
    }
}

// ---------------------------------------------------------------------------
extern "C" void kernel_launch(void* const* d_in, const int* in_sizes, int n_in,
                              void* d_out, int out_size, void* d_ws, size_t ws_size,
                              hipStream_t stream) {
  const float* u         = (const float*)d_in[0];
  const float* nu_log    = (const float*)d_in[1];
  const float* theta_log = (const float*)d_in[2];
  const float* gamma_log = (const float*)d_in[3];
  const float* Bp_re     = (const float*)d_in[4];
  const float* Bp_im     = (const float*)d_in[5];
  const float* C_re      = (const float*)d_in[6];
  const float* C_im      = (const float*)d_in[7];
  const float* D         = (const float*)d_in[8];

  float* y = (float*)d_out;
  char* wsb = (char*)d_ws;

  // ws layout (bytes)
  float*  lamRe  = (float*)(wsb + 0);
  float*  lamIm  = lamRe + NS;
  float*  lamPRe = lamIm + NS;
  float*  lamPIm = lamPRe + NS;                         // end 4096
  __bf16* Bfi_h  = (__bf16*)(wsb + 4096);               // 131072 B
  __bf16* Bfi_l  = (__bf16*)(wsb + 4096 + 131072);      // 131072 B
  __bf16* Wf_h   = (__bf16*)(wsb + 266240);             // 163840 B
  __bf16* Wf_l   = (__bf16*)(wsb + 266240 + 163840);    // ends 593920
  float*  imP    = (float*)(wsb + 593920);              // Bu.im, stateFloats

  const size_t stateFloats = (size_t)BATCH * SROWB * NS;  // 16,779,264
  float* carries = imP + stateFloats;                     // 524288 f32 (2 MB)
  const size_t needWs = 593920 + (stateFloats + 524288) * 4;  // ~69.8 MB (HW-OK)

  if (out_size < (int)(Y_FLOATS + stateFloats) ||
      out_size >= (int)(Y_FLOATS + 2 * stateFloats))
    return;
  if (ws_size < needWs) return;  // clean fail -> diagnostic, no OOB
  float* reP = y + Y_FLOATS;

  setup_small<<<1, 256, 0, stream>>>(nu_log, theta_log, gamma_log, Bp_re, Bp_im,
                                     Bfi_h, Bfi_l, lamRe, lamIm, lamPRe, lamPIm);
  setup_Wfrag<<<320, 256, 0, stream>>>(C_re, C_im, D, Wf_h, Wf_l);
  gemm_bu_mfma<<<2048, 256, 0, stream>>>(u, Bfi_h, Bfi_l, reP, imP);
  scanA<<<BATCH * NCH, 256, 0, stream>>>(reP, imP, lamRe, lamIm, carries);
  scanB<<<BATCH, 256, 0, stream>>>(carries, lamPRe, lamPIm);
  scan_gemm_y<<<dim3(NCH, BATCH), 256, 0, stream>>>(
      reP, imP, u, Wf_h, Wf_l, lamRe, lamIm, carries, y);
}